// Round 9
// baseline (517.811 us; speedup 1.0000x reference)
//
#include <hip/hip_runtime.h>

// ---------------- tiny zero ----------------

__global__ void k_zero(int* __restrict__ p, int n) {
    int i = threadIdx.x;
    if (i < n) p[i] = 0;
}

// ---------------- partition: edges -> coarse buckets (256 nodes each) ----------------

#define PCHUNK 8192
#define PTHREADS 512
#define NBUCK_MAX 400
#define BCAP 6144

__global__ __launch_bounds__(PTHREADS)
void k_partition2(const int* __restrict__ src, const int* __restrict__ dst,
                  int* __restrict__ bcnt, unsigned int* __restrict__ stageg,
                  int E, int nbuck) {
    __shared__ int hist[NBUCK_MAX];
    __shared__ int boffs[NBUCK_MAX];
    __shared__ int cur[NBUCK_MAX];
    __shared__ int gbase[NBUCK_MAX];
    __shared__ int tmp[PTHREADS];
    __shared__ unsigned int stage[PCHUNK];
    __shared__ unsigned short sbid[PCHUNK];

    int tid = threadIdx.x;
    int ebase = blockIdx.x * PCHUNK;
    int ecount = min(PCHUNK, E - ebase);

    if (tid < NBUCK_MAX) hist[tid] = 0;
    __syncthreads();

    int dreg[16], sreg[16];
#pragma unroll
    for (int k = 0; k < 16; k++) {
        int e = ebase + tid + k * PTHREADS;
        if (tid + k * PTHREADS < ecount) {
            dreg[k] = dst[e];
            sreg[k] = src[e];
            atomicAdd(&hist[dreg[k] >> 8], 1);
        } else dreg[k] = -1;
    }
    __syncthreads();

    int v = (tid < nbuck) ? hist[tid] : 0;
    tmp[tid] = v;
    __syncthreads();
    for (int d = 1; d < PTHREADS; d <<= 1) {
        int t = (tid >= d) ? tmp[tid - d] : 0;
        __syncthreads();
        tmp[tid] += t;
        __syncthreads();
    }
    if (tid < nbuck) { boffs[tid] = tmp[tid] - v; cur[tid] = tmp[tid] - v; }
    __syncthreads();

#pragma unroll
    for (int k = 0; k < 16; k++) {
        if (dreg[k] >= 0) {
            int b = dreg[k] >> 8;
            int p = atomicAdd(&cur[b], 1);
            stage[p] = ((unsigned int)(dreg[k] & 255) << 17) | (unsigned int)sreg[k];
            sbid[p] = (unsigned short)b;
        }
    }
    __syncthreads();

    if (tid < nbuck) {
        int c = cur[tid] - boffs[tid];
        if (c > 0) gbase[tid] = atomicAdd(&bcnt[tid], c);
    }
    __syncthreads();

    for (int i = tid; i < ecount; i += PTHREADS) {
        int b = sbid[i];
        stageg[(size_t)b * BCAP + gbase[b] + (i - boffs[b])] = stage[i];
    }
}

// ---------------- bucket scan ----------------

__global__ __launch_bounds__(512)
void k_bucket_scan(const int* __restrict__ bcnt, int* __restrict__ bbase, int nbuck) {
    __shared__ int tmp[512];
    int tid = threadIdx.x;
    int v = (tid < nbuck) ? bcnt[tid] : 0;
    tmp[tid] = v;
    __syncthreads();
    for (int d = 1; d < 512; d <<= 1) {
        int t = (tid >= d) ? tmp[tid - d] : 0;
        __syncthreads();
        tmp[tid] += t;
        __syncthreads();
    }
    if (tid < nbuck) bbase[tid] = tmp[tid] - v;
    if (tid == nbuck - 1) bbase[nbuck] = tmp[tid];
}

// ---------------- fine fill: bucket-staged -> dense CSR (offs, dinv, col) ----------------

__global__ __launch_bounds__(1024)
void k_finefill2(const unsigned int* __restrict__ stageg, const int* __restrict__ bcnt,
                 const int* __restrict__ bbase, int* __restrict__ offs,
                 float* __restrict__ dinv, int* __restrict__ col, int N, int nbuck) {
    __shared__ int cnt0[256];
    __shared__ int excl[256];
    __shared__ int cur[256];
    __shared__ unsigned int stage[BCAP];
    int b = blockIdx.x;
    int tid = threadIdx.x;
    int nbase = b << 8;
    int nn = min(256, N - nbase);
    int n = bcnt[b];
    int base = bbase[b];
    const unsigned int* sg = stageg + (size_t)b * BCAP;

    if (tid < 256) cnt0[tid] = 0;
    __syncthreads();

    for (int i = tid; i < n; i += 1024)
        atomicAdd(&cnt0[sg[i] >> 17], 1);
    __syncthreads();

    if (tid < 256) excl[tid] = cnt0[tid];
    __syncthreads();
    for (int d = 1; d < 256; d <<= 1) {
        int t = 0;
        if (tid < 256 && tid >= d) t = excl[tid - d];
        __syncthreads();
        if (tid < 256) excl[tid] += t;
        __syncthreads();
    }
    if (tid < 256) {
        int e = excl[tid] - cnt0[tid];
        cur[tid] = e;
        if (tid < nn) {
            offs[nbase + tid] = base + e;
            dinv[nbase + tid] = rsqrtf((float)(cnt0[tid] + 1));  // +1 self-loop
        }
    }
    if (b == nbuck - 1 && tid == 0) offs[N] = bbase[nbuck];
    __syncthreads();

    for (int i = tid; i < n; i += 1024) {
        unsigned int v = sg[i];
        int p = atomicAdd(&cur[v >> 17], 1);
        stage[p] = v & 0x1FFFFu;
    }
    __syncthreads();
    for (int i = tid; i < n; i += 1024)
        col[base + i] = (int)stage[i];
}

// ---------------- bf16 helpers ----------------

__device__ __forceinline__ unsigned int bf16rne(float x) {
    unsigned int u = __float_as_uint(x);
    return (u + 0x7FFFu + ((u >> 16) & 1u)) >> 16;
}
__device__ __forceinline__ float u2flo(unsigned int u) { return __uint_as_float(u << 16); }
__device__ __forceinline__ float u2fhi(unsigned int u) { return __uint_as_float(u & 0xFFFF0000u); }

// ---------------- Register GEMM: out[r][:] = (A[r][:] @ W) (+bias) (*scale[r]) ----------------
// W/bias via wave-uniform s_load (scalar cache broadcast). a[64]+acc[64] MUST be
// register-resident: __launch_bounds__(256,2) gives the allocator a 256-VGPR
// budget (round-8 failure: default heuristic allocated 40 VGPRs, sliced the
// c-loop and re-loaded A per slice -> 6% VALUBusy). The asm "+v" pins make a[]
// opaque so A cannot be re-materialized from memory.

template <bool HAS_BIAS, bool SCALE, bool OUTBF16>
__global__ __launch_bounds__(256, 2)
void k_gemm_reg(const float* __restrict__ A, const float* __restrict__ W,
                const float* __restrict__ bias, const float* __restrict__ scale,
                void* __restrict__ out, int N) {
    int r = blockIdx.x * 256 + threadIdx.x;
    if (r >= N) return;

    float a[64];
    const float4* a4 = (const float4*)(A + (size_t)r * 64);
#pragma unroll
    for (int i = 0; i < 16; i++) {
        float4 v = a4[i];
        a[4 * i] = v.x; a[4 * i + 1] = v.y; a[4 * i + 2] = v.z; a[4 * i + 3] = v.w;
    }
#pragma unroll
    for (int k = 0; k < 64; k++) asm volatile("" : "+v"(a[k]));

    float acc[64];
#pragma unroll
    for (int c = 0; c < 64; c++) acc[c] = HAS_BIAS ? bias[c] : 0.f;

#pragma unroll
    for (int k = 0; k < 64; k++) {
        const float* wr = W + k * 64;
        float xk = a[k];
#pragma unroll
        for (int c = 0; c < 64; c++) acc[c] = fmaf(xk, wr[c], acc[c]);
    }

    float s = SCALE ? scale[r] : 1.0f;
    if (OUTBF16) {
        uint2* o2 = (uint2*)((unsigned short*)out + (size_t)r * 64);
#pragma unroll
        for (int c4 = 0; c4 < 16; c4++) {
            float v0 = acc[4 * c4], v1 = acc[4 * c4 + 1], v2 = acc[4 * c4 + 2], v3 = acc[4 * c4 + 3];
            if (SCALE) { v0 *= s; v1 *= s; v2 *= s; v3 *= s; }
            unsigned int lo = bf16rne(v0) | (bf16rne(v1) << 16);
            unsigned int hi = bf16rne(v2) | (bf16rne(v3) << 16);
            o2[c4] = make_uint2(lo, hi);
        }
    } else {
        float4* o4 = (float4*)((float*)out + (size_t)r * 64);
#pragma unroll
        for (int c4 = 0; c4 < 16; c4++) {
            float4 v = make_float4(acc[4 * c4], acc[4 * c4 + 1], acc[4 * c4 + 2], acc[4 * c4 + 3]);
            if (SCALE) { v.x *= s; v.y *= s; v.z *= s; v.w *= s; }
            o4[c4] = v;
        }
    }
}

// ---------------- Aggregation: one wave per 8 NODES (group=node, lane=8 channels) ----------------

__global__ __launch_bounds__(256)
void k_agg(const unsigned short* __restrict__ hwb, const int* __restrict__ offs,
           const int* __restrict__ col, const float* __restrict__ dinv,
           const float* __restrict__ bg, float* __restrict__ h, int N, int relu) {
    int t = blockIdx.x * blockDim.x + threadIdx.x;
    int wid = t >> 6;
    int lane = threadIdx.x & 63;
    int G = lane >> 3;
    int L = lane & 7;
    int node = wid * 8 + G;
    bool valid = node < N;
    int nc = valid ? node : N - 1;

    int start = offs[nc];
    int end = valid ? offs[nc + 1] : start;

    uint4 v = ((const uint4*)(hwb + (size_t)nc * 64))[L];
    float a0 = u2flo(v.x), a1 = u2fhi(v.x);
    float a2 = u2flo(v.y), a3 = u2fhi(v.y);
    float a4 = u2flo(v.z), a5 = u2fhi(v.z);
    float a6 = u2flo(v.w), a7 = u2fhi(v.w);

    for (int e = start;; e += 2) {
        bool act0 = e < end;
        if (__ballot(act0) == 0ULL) break;
        bool act1 = e + 1 < end;
        int e0 = act0 ? e : 0;
        int e1 = act1 ? e + 1 : 0;
        int s0 = col[e0];
        int s1 = col[e1];
        uint4 v0 = ((const uint4*)(hwb + (size_t)s0 * 64))[L];
        uint4 v1 = ((const uint4*)(hwb + (size_t)s1 * 64))[L];
        if (!act0) { v0.x = 0u; v0.y = 0u; v0.z = 0u; v0.w = 0u; }
        if (!act1) { v1.x = 0u; v1.y = 0u; v1.z = 0u; v1.w = 0u; }
        a0 += u2flo(v0.x) + u2flo(v1.x);
        a1 += u2fhi(v0.x) + u2fhi(v1.x);
        a2 += u2flo(v0.y) + u2flo(v1.y);
        a3 += u2fhi(v0.y) + u2fhi(v1.y);
        a4 += u2flo(v0.z) + u2flo(v1.z);
        a5 += u2fhi(v0.z) + u2fhi(v1.z);
        a6 += u2flo(v0.w) + u2flo(v1.w);
        a7 += u2fhi(v0.w) + u2fhi(v1.w);
    }

    if (valid) {
        float dn = dinv[node];
        float* hrow = h + (size_t)node * 64 + L * 8;
        float4 r0 = ((const float4*)hrow)[0];
        float4 r1 = ((const float4*)hrow)[1];
        const float* bgp = bg + L * 8;
        float4 b0 = ((const float4*)bgp)[0];
        float4 b1 = ((const float4*)bgp)[1];
        float4 o0, o1;
        o0.x = fmaf(dn, a0, b0.x + r0.x);
        o0.y = fmaf(dn, a1, b0.y + r0.y);
        o0.z = fmaf(dn, a2, b0.z + r0.z);
        o0.w = fmaf(dn, a3, b0.w + r0.w);
        o1.x = fmaf(dn, a4, b1.x + r1.x);
        o1.y = fmaf(dn, a5, b1.y + r1.y);
        o1.z = fmaf(dn, a6, b1.z + r1.z);
        o1.w = fmaf(dn, a7, b1.w + r1.w);
        if (relu) {
            o0.x = fmaxf(o0.x, 0.f); o0.y = fmaxf(o0.y, 0.f);
            o0.z = fmaxf(o0.z, 0.f); o0.w = fmaxf(o0.w, 0.f);
            o1.x = fmaxf(o1.x, 0.f); o1.y = fmaxf(o1.y, 0.f);
            o1.z = fmaxf(o1.z, 0.f); o1.w = fmaxf(o1.w, 0.f);
        }
        ((float4*)hrow)[0] = o0;
        ((float4*)hrow)[1] = o1;
    }
}

// ---------------- Fused MLP readout: 64 -> 32 -> 16 -> 1 (fully unrolled) ----------------

__global__ __launch_bounds__(256)
void k_readout(const float* __restrict__ h,
               const float* __restrict__ W0, const float* __restrict__ b0,
               const float* __restrict__ W1, const float* __restrict__ b1,
               const float* __restrict__ W2, const float* __restrict__ b2,
               float* __restrict__ out, int N) {
    int r = blockIdx.x * 256 + threadIdx.x;
    if (r >= N) return;

    float t0[32];
#pragma unroll
    for (int c = 0; c < 32; c++) t0[c] = b0[c];

    const float4* h4 = (const float4*)(h + (size_t)r * 64);
#pragma unroll
    for (int k4 = 0; k4 < 16; k4++) {
        float4 v = h4[k4];
#pragma unroll
        for (int kk = 0; kk < 4; kk++) {
            float xk = (kk == 0) ? v.x : (kk == 1) ? v.y : (kk == 2) ? v.z : v.w;
            const float* wr = W0 + (k4 * 4 + kk) * 32;
#pragma unroll
            for (int c = 0; c < 32; c++) t0[c] = fmaf(xk, wr[c], t0[c]);
        }
    }
#pragma unroll
    for (int c = 0; c < 32; c++) t0[c] = fmaxf(t0[c], 0.f);

    float t1[16];
#pragma unroll
    for (int c = 0; c < 16; c++) t1[c] = b1[c];
#pragma unroll
    for (int k = 0; k < 32; k++) {
        const float* wr = W1 + k * 16;
#pragma unroll
        for (int c = 0; c < 16; c++) t1[c] = fmaf(t0[k], wr[c], t1[c]);
    }
#pragma unroll
    for (int c = 0; c < 16; c++) t1[c] = fmaxf(t1[c], 0.f);

    float y = b2[0];
#pragma unroll
    for (int k = 0; k < 16; k++) y = fmaf(t1[k], W2[k], y);
    out[r] = y;
}

// ---------------- launch ----------------

extern "C" void kernel_launch(void* const* d_in, const int* in_sizes, int n_in,
                              void* d_out, int out_size, void* d_ws, size_t ws_size,
                              hipStream_t stream) {
    const float* x     = (const float*)d_in[0];
    const int*   eidx  = (const int*)d_in[1];
    const float* W_enc = (const float*)d_in[2];
    const float* b_enc = (const float*)d_in[3];
    const float* Wg    = (const float*)d_in[4];
    const float* bg    = (const float*)d_in[5];
    const float* W0    = (const float*)d_in[6];
    const float* b0    = (const float*)d_in[7];
    const float* W1    = (const float*)d_in[8];
    const float* b1    = (const float*)d_in[9];
    const float* W2    = (const float*)d_in[10];
    const float* b2    = (const float*)d_in[11];

    int N = in_sizes[0] / 64;
    int E = in_sizes[1] / 2;
    const int* esrc = eidx;
    const int* edst = eidx + E;
    int nbuck = (N + 255) >> 8;

    char* w = (char*)d_ws;
    auto alloc = [&](size_t bytes) -> char* {
        char* p = w;
        w += (bytes + 255) & ~(size_t)255;
        return p;
    };
    int*   bcnt  = (int*)alloc(512 * 4);
    int*   bbase = (int*)alloc(512 * 4);
    int*   offs  = (int*)alloc((size_t)(N + 1) * 4);
    int*   col   = (int*)alloc((size_t)E * 4);
    unsigned int* stageg = (unsigned int*)alloc((size_t)nbuck * BCAP * 4);
    float* dinv  = (float*)alloc((size_t)N * 4);
    float* h     = (float*)alloc((size_t)N * 64 * 4);
    unsigned short* hwb = (unsigned short*)alloc((size_t)N * 64 * 2);

    k_zero<<<1, 512, 0, stream>>>(bcnt, 512);
    k_partition2<<<(E + PCHUNK - 1) / PCHUNK, PTHREADS, 0, stream>>>(esrc, edst, bcnt, stageg, E, nbuck);
    k_bucket_scan<<<1, 512, 0, stream>>>(bcnt, bbase, nbuck);
    k_finefill2<<<nbuck, 1024, 0, stream>>>(stageg, bcnt, bbase, offs, dinv, col, N, nbuck);

    int gb = (N + 255) / 256;
    int aggthreads = ((N + 7) / 8) * 64;
    int aggblocks = (aggthreads + 255) / 256;
    k_gemm_reg<true, false, false><<<gb, 256, 0, stream>>>(x, W_enc, b_enc, nullptr, h, N);
    for (int l = 0; l < 4; l++) {
        k_gemm_reg<false, true, true><<<gb, 256, 0, stream>>>(h, Wg + (size_t)l * 4096, nullptr, dinv, hwb, N);
        k_agg<<<aggblocks, 256, 0, stream>>>(
            hwb, offs, col, dinv, bg + (size_t)l * 64, h, N, (l != 3) ? 1 : 0);
    }
    k_readout<<<gb, 256, 0, stream>>>(h, W0, b0, W1, b1, W2, b2, (float*)d_out, N);
}

// Round 10
// 339.295 us; speedup vs baseline: 1.5261x; 1.5261x over previous
//
#include <hip/hip_runtime.h>

// ---------------- tiny zero ----------------

__global__ void k_zero(int* __restrict__ p, int n) {
    int i = threadIdx.x;
    if (i < n) p[i] = 0;
}

// ---------------- partition: edges -> coarse buckets (256 nodes each) ----------------

#define PCHUNK 8192
#define PTHREADS 512
#define NBUCK_MAX 400
#define BCAP 6144

__global__ __launch_bounds__(PTHREADS)
void k_partition2(const int* __restrict__ src, const int* __restrict__ dst,
                  int* __restrict__ bcnt, unsigned int* __restrict__ stageg,
                  int E, int nbuck) {
    __shared__ int hist[NBUCK_MAX];
    __shared__ int boffs[NBUCK_MAX];
    __shared__ int cur[NBUCK_MAX];
    __shared__ int gbase[NBUCK_MAX];
    __shared__ int tmp[PTHREADS];
    __shared__ unsigned int stage[PCHUNK];
    __shared__ unsigned short sbid[PCHUNK];

    int tid = threadIdx.x;
    int ebase = blockIdx.x * PCHUNK;
    int ecount = min(PCHUNK, E - ebase);

    if (tid < NBUCK_MAX) hist[tid] = 0;
    __syncthreads();

    int dreg[16], sreg[16];
#pragma unroll
    for (int k = 0; k < 16; k++) {
        int e = ebase + tid + k * PTHREADS;
        if (tid + k * PTHREADS < ecount) {
            dreg[k] = dst[e];
            sreg[k] = src[e];
            atomicAdd(&hist[dreg[k] >> 8], 1);
        } else dreg[k] = -1;
    }
    __syncthreads();

    int v = (tid < nbuck) ? hist[tid] : 0;
    tmp[tid] = v;
    __syncthreads();
    for (int d = 1; d < PTHREADS; d <<= 1) {
        int t = (tid >= d) ? tmp[tid - d] : 0;
        __syncthreads();
        tmp[tid] += t;
        __syncthreads();
    }
    if (tid < nbuck) { boffs[tid] = tmp[tid] - v; cur[tid] = tmp[tid] - v; }
    __syncthreads();

#pragma unroll
    for (int k = 0; k < 16; k++) {
        if (dreg[k] >= 0) {
            int b = dreg[k] >> 8;
            int p = atomicAdd(&cur[b], 1);
            stage[p] = ((unsigned int)(dreg[k] & 255) << 17) | (unsigned int)sreg[k];
            sbid[p] = (unsigned short)b;
        }
    }
    __syncthreads();

    if (tid < nbuck) {
        int c = cur[tid] - boffs[tid];
        if (c > 0) gbase[tid] = atomicAdd(&bcnt[tid], c);
    }
    __syncthreads();

    for (int i = tid; i < ecount; i += PTHREADS) {
        int b = sbid[i];
        stageg[(size_t)b * BCAP + gbase[b] + (i - boffs[b])] = stage[i];
    }
}

// ---------------- bucket scan ----------------

__global__ __launch_bounds__(512)
void k_bucket_scan(const int* __restrict__ bcnt, int* __restrict__ bbase, int nbuck) {
    __shared__ int tmp[512];
    int tid = threadIdx.x;
    int v = (tid < nbuck) ? bcnt[tid] : 0;
    tmp[tid] = v;
    __syncthreads();
    for (int d = 1; d < 512; d <<= 1) {
        int t = (tid >= d) ? tmp[tid - d] : 0;
        __syncthreads();
        tmp[tid] += t;
        __syncthreads();
    }
    if (tid < nbuck) bbase[tid] = tmp[tid] - v;
    if (tid == nbuck - 1) bbase[nbuck] = tmp[tid];
}

// ---------------- fine fill: bucket-staged -> dense CSR (offs, dinv, col) ----------------

__global__ __launch_bounds__(1024)
void k_finefill2(const unsigned int* __restrict__ stageg, const int* __restrict__ bcnt,
                 const int* __restrict__ bbase, int* __restrict__ offs,
                 float* __restrict__ dinv, int* __restrict__ col, int N, int nbuck) {
    __shared__ int cnt0[256];
    __shared__ int excl[256];
    __shared__ int cur[256];
    __shared__ unsigned int stage[BCAP];
    int b = blockIdx.x;
    int tid = threadIdx.x;
    int nbase = b << 8;
    int nn = min(256, N - nbase);
    int n = bcnt[b];
    int base = bbase[b];
    const unsigned int* sg = stageg + (size_t)b * BCAP;

    if (tid < 256) cnt0[tid] = 0;
    __syncthreads();

    for (int i = tid; i < n; i += 1024)
        atomicAdd(&cnt0[sg[i] >> 17], 1);
    __syncthreads();

    if (tid < 256) excl[tid] = cnt0[tid];
    __syncthreads();
    for (int d = 1; d < 256; d <<= 1) {
        int t = 0;
        if (tid < 256 && tid >= d) t = excl[tid - d];
        __syncthreads();
        if (tid < 256) excl[tid] += t;
        __syncthreads();
    }
    if (tid < 256) {
        int e = excl[tid] - cnt0[tid];
        cur[tid] = e;
        if (tid < nn) {
            offs[nbase + tid] = base + e;
            dinv[nbase + tid] = rsqrtf((float)(cnt0[tid] + 1));  // +1 self-loop
        }
    }
    if (b == nbuck - 1 && tid == 0) offs[N] = bbase[nbuck];
    __syncthreads();

    for (int i = tid; i < n; i += 1024) {
        unsigned int v = sg[i];
        int p = atomicAdd(&cur[v >> 17], 1);
        stage[p] = v & 0x1FFFFu;
    }
    __syncthreads();
    for (int i = tid; i < n; i += 1024)
        col[base + i] = (int)stage[i];
}

// ---------------- bf16 helpers ----------------

__device__ __forceinline__ unsigned int bf16rne(float x) {
    unsigned int u = __float_as_uint(x);
    return (u + 0x7FFFu + ((u >> 16) & 1u)) >> 16;
}
__device__ __forceinline__ float u2flo(unsigned int u) { return __uint_as_float(u << 16); }
__device__ __forceinline__ float u2fhi(unsigned int u) { return __uint_as_float(u & 0xFFFF0000u); }

// ---------------- Wave-chunk GEMM: out[r][:] = (A[r][:] @ W) (+bias) (*scale[r]) ----------------
// Block = 256 threads = 4 waves over the SAME 64 rows; wave w owns columns
// [w*16, w*16+16). Per-thread state a[64]+acc[16] (~90 VGPR) fits the
// launch_bounds(256,4) budget of 128 -> no column slicing (round-8/9 failure).
// W base made wave-uniform via readfirstlane -> SGPR base -> s_load_dwordx16
// per k (scalar-cache broadcast, the proven k_readout path). Grid = N/64 blocks
// (4x round-9's waves), so s_load latency hides behind ~16 waves/CU.

template <bool HAS_BIAS, bool SCALE, bool OUTBF16>
__global__ __launch_bounds__(256, 4)
void k_gemm_wave(const float* __restrict__ A, const float* __restrict__ W,
                 const float* __restrict__ bias, const float* __restrict__ scale,
                 void* __restrict__ out, int N) {
    int lane = threadIdx.x & 63;
    int wv = __builtin_amdgcn_readfirstlane(threadIdx.x >> 6);  // SGPR column chunk
    const float* Wc = W + wv * 16;
    const float* bc = HAS_BIAS ? bias + wv * 16 : nullptr;

    int r = blockIdx.x * 64 + lane;
    if (r >= N) return;

    float a[64];
    const float4* a4 = (const float4*)(A + (size_t)r * 64);
#pragma unroll
    for (int i = 0; i < 16; i++) {
        float4 v = a4[i];
        a[4 * i] = v.x; a[4 * i + 1] = v.y; a[4 * i + 2] = v.z; a[4 * i + 3] = v.w;
    }
#pragma unroll
    for (int k = 0; k < 64; k++) asm volatile("" : "+v"(a[k]));

    float acc[16];
#pragma unroll
    for (int c = 0; c < 16; c++) acc[c] = HAS_BIAS ? bc[c] : 0.f;

#pragma unroll
    for (int k = 0; k < 64; k++) {
        const float* wr = Wc + k * 64;   // wave-uniform: s_load_dwordx16
        float xk = a[k];
#pragma unroll
        for (int c = 0; c < 16; c++) acc[c] = fmaf(xk, wr[c], acc[c]);
    }

    float s = SCALE ? scale[r] : 1.0f;
    if (OUTBF16) {
        // 16 bf16 = 32B at ((r*64)+wv*16)*2 bytes: 2x uint4, 32B-aligned
        uint4* o4 = (uint4*)((unsigned short*)out + (size_t)r * 64 + wv * 16);
#pragma unroll
        for (int q = 0; q < 2; q++) {
            float v0 = acc[8 * q + 0], v1 = acc[8 * q + 1], v2 = acc[8 * q + 2], v3 = acc[8 * q + 3];
            float v4 = acc[8 * q + 4], v5 = acc[8 * q + 5], v6 = acc[8 * q + 6], v7 = acc[8 * q + 7];
            if (SCALE) { v0 *= s; v1 *= s; v2 *= s; v3 *= s; v4 *= s; v5 *= s; v6 *= s; v7 *= s; }
            uint4 o;
            o.x = bf16rne(v0) | (bf16rne(v1) << 16);
            o.y = bf16rne(v2) | (bf16rne(v3) << 16);
            o.z = bf16rne(v4) | (bf16rne(v5) << 16);
            o.w = bf16rne(v6) | (bf16rne(v7) << 16);
            o4[q] = o;
        }
    } else {
        float4* o4 = (float4*)((float*)out + (size_t)r * 64 + wv * 16);
#pragma unroll
        for (int q = 0; q < 4; q++) {
            float4 v = make_float4(acc[4 * q], acc[4 * q + 1], acc[4 * q + 2], acc[4 * q + 3]);
            if (SCALE) { v.x *= s; v.y *= s; v.z *= s; v.w *= s; }
            o4[q] = v;
        }
    }
}

// ---------------- Aggregation: one wave per 8 NODES (group=node, lane=8 channels) ----------------

__global__ __launch_bounds__(256)
void k_agg(const unsigned short* __restrict__ hwb, const int* __restrict__ offs,
           const int* __restrict__ col, const float* __restrict__ dinv,
           const float* __restrict__ bg, float* __restrict__ h, int N, int relu) {
    int t = blockIdx.x * blockDim.x + threadIdx.x;
    int wid = t >> 6;
    int lane = threadIdx.x & 63;
    int G = lane >> 3;
    int L = lane & 7;
    int node = wid * 8 + G;
    bool valid = node < N;
    int nc = valid ? node : N - 1;

    int start = offs[nc];
    int end = valid ? offs[nc + 1] : start;

    uint4 v = ((const uint4*)(hwb + (size_t)nc * 64))[L];
    float a0 = u2flo(v.x), a1 = u2fhi(v.x);
    float a2 = u2flo(v.y), a3 = u2fhi(v.y);
    float a4 = u2flo(v.z), a5 = u2fhi(v.z);
    float a6 = u2flo(v.w), a7 = u2fhi(v.w);

    for (int e = start;; e += 2) {
        bool act0 = e < end;
        if (__ballot(act0) == 0ULL) break;
        bool act1 = e + 1 < end;
        int e0 = act0 ? e : 0;
        int e1 = act1 ? e + 1 : 0;
        int s0 = col[e0];
        int s1 = col[e1];
        uint4 v0 = ((const uint4*)(hwb + (size_t)s0 * 64))[L];
        uint4 v1 = ((const uint4*)(hwb + (size_t)s1 * 64))[L];
        if (!act0) { v0.x = 0u; v0.y = 0u; v0.z = 0u; v0.w = 0u; }
        if (!act1) { v1.x = 0u; v1.y = 0u; v1.z = 0u; v1.w = 0u; }
        a0 += u2flo(v0.x) + u2flo(v1.x);
        a1 += u2fhi(v0.x) + u2fhi(v1.x);
        a2 += u2flo(v0.y) + u2flo(v1.y);
        a3 += u2fhi(v0.y) + u2fhi(v1.y);
        a4 += u2flo(v0.z) + u2flo(v1.z);
        a5 += u2fhi(v0.z) + u2fhi(v1.z);
        a6 += u2flo(v0.w) + u2flo(v1.w);
        a7 += u2fhi(v0.w) + u2fhi(v1.w);
    }

    if (valid) {
        float dn = dinv[node];
        float* hrow = h + (size_t)node * 64 + L * 8;
        float4 r0 = ((const float4*)hrow)[0];
        float4 r1 = ((const float4*)hrow)[1];
        const float* bgp = bg + L * 8;
        float4 b0 = ((const float4*)bgp)[0];
        float4 b1 = ((const float4*)bgp)[1];
        float4 o0, o1;
        o0.x = fmaf(dn, a0, b0.x + r0.x);
        o0.y = fmaf(dn, a1, b0.y + r0.y);
        o0.z = fmaf(dn, a2, b0.z + r0.z);
        o0.w = fmaf(dn, a3, b0.w + r0.w);
        o1.x = fmaf(dn, a4, b1.x + r1.x);
        o1.y = fmaf(dn, a5, b1.y + r1.y);
        o1.z = fmaf(dn, a6, b1.z + r1.z);
        o1.w = fmaf(dn, a7, b1.w + r1.w);
        if (relu) {
            o0.x = fmaxf(o0.x, 0.f); o0.y = fmaxf(o0.y, 0.f);
            o0.z = fmaxf(o0.z, 0.f); o0.w = fmaxf(o0.w, 0.f);
            o1.x = fmaxf(o1.x, 0.f); o1.y = fmaxf(o1.y, 0.f);
            o1.z = fmaxf(o1.z, 0.f); o1.w = fmaxf(o1.w, 0.f);
        }
        ((float4*)hrow)[0] = o0;
        ((float4*)hrow)[1] = o1;
    }
}

// ---------------- Fused MLP readout: 64 -> 32 -> 16 -> 1 (fully unrolled) ----------------

__global__ __launch_bounds__(256)
void k_readout(const float* __restrict__ h,
               const float* __restrict__ W0, const float* __restrict__ b0,
               const float* __restrict__ W1, const float* __restrict__ b1,
               const float* __restrict__ W2, const float* __restrict__ b2,
               float* __restrict__ out, int N) {
    int r = blockIdx.x * 256 + threadIdx.x;
    if (r >= N) return;

    float t0[32];
#pragma unroll
    for (int c = 0; c < 32; c++) t0[c] = b0[c];

    const float4* h4 = (const float4*)(h + (size_t)r * 64);
#pragma unroll
    for (int k4 = 0; k4 < 16; k4++) {
        float4 v = h4[k4];
#pragma unroll
        for (int kk = 0; kk < 4; kk++) {
            float xk = (kk == 0) ? v.x : (kk == 1) ? v.y : (kk == 2) ? v.z : v.w;
            const float* wr = W0 + (k4 * 4 + kk) * 32;
#pragma unroll
            for (int c = 0; c < 32; c++) t0[c] = fmaf(xk, wr[c], t0[c]);
        }
    }
#pragma unroll
    for (int c = 0; c < 32; c++) t0[c] = fmaxf(t0[c], 0.f);

    float t1[16];
#pragma unroll
    for (int c = 0; c < 16; c++) t1[c] = b1[c];
#pragma unroll
    for (int k = 0; k < 32; k++) {
        const float* wr = W1 + k * 16;
#pragma unroll
        for (int c = 0; c < 16; c++) t1[c] = fmaf(t0[k], wr[c], t1[c]);
    }
#pragma unroll
    for (int c = 0; c < 16; c++) t1[c] = fmaxf(t1[c], 0.f);

    float y = b2[0];
#pragma unroll
    for (int k = 0; k < 16; k++) y = fmaf(t1[k], W2[k], y);
    out[r] = y;
}

// ---------------- launch ----------------

extern "C" void kernel_launch(void* const* d_in, const int* in_sizes, int n_in,
                              void* d_out, int out_size, void* d_ws, size_t ws_size,
                              hipStream_t stream) {
    const float* x     = (const float*)d_in[0];
    const int*   eidx  = (const int*)d_in[1];
    const float* W_enc = (const float*)d_in[2];
    const float* b_enc = (const float*)d_in[3];
    const float* Wg    = (const float*)d_in[4];
    const float* bg    = (const float*)d_in[5];
    const float* W0    = (const float*)d_in[6];
    const float* b0    = (const float*)d_in[7];
    const float* W1    = (const float*)d_in[8];
    const float* b1    = (const float*)d_in[9];
    const float* W2    = (const float*)d_in[10];
    const float* b2    = (const float*)d_in[11];

    int N = in_sizes[0] / 64;
    int E = in_sizes[1] / 2;
    const int* esrc = eidx;
    const int* edst = eidx + E;
    int nbuck = (N + 255) >> 8;

    char* w = (char*)d_ws;
    auto alloc = [&](size_t bytes) -> char* {
        char* p = w;
        w += (bytes + 255) & ~(size_t)255;
        return p;
    };
    int*   bcnt  = (int*)alloc(512 * 4);
    int*   bbase = (int*)alloc(512 * 4);
    int*   offs  = (int*)alloc((size_t)(N + 1) * 4);
    int*   col   = (int*)alloc((size_t)E * 4);
    unsigned int* stageg = (unsigned int*)alloc((size_t)nbuck * BCAP * 4);
    float* dinv  = (float*)alloc((size_t)N * 4);
    float* h     = (float*)alloc((size_t)N * 64 * 4);
    unsigned short* hwb = (unsigned short*)alloc((size_t)N * 64 * 2);

    k_zero<<<1, 512, 0, stream>>>(bcnt, 512);
    k_partition2<<<(E + PCHUNK - 1) / PCHUNK, PTHREADS, 0, stream>>>(esrc, edst, bcnt, stageg, E, nbuck);
    k_bucket_scan<<<1, 512, 0, stream>>>(bcnt, bbase, nbuck);
    k_finefill2<<<nbuck, 1024, 0, stream>>>(stageg, bcnt, bbase, offs, dinv, col, N, nbuck);

    int gb64 = (N + 63) / 64;       // wave-chunk GEMM: 64 rows per block
    int gb = (N + 255) / 256;
    int aggthreads = ((N + 7) / 8) * 64;
    int aggblocks = (aggthreads + 255) / 256;
    k_gemm_wave<true, false, false><<<gb64, 256, 0, stream>>>(x, W_enc, b_enc, nullptr, h, N);
    for (int l = 0; l < 4; l++) {
        k_gemm_wave<false, true, true><<<gb64, 256, 0, stream>>>(h, Wg + (size_t)l * 4096, nullptr, dinv, hwb, N);
        k_agg<<<aggblocks, 256, 0, stream>>>(
            hwb, offs, col, dinv, bg + (size_t)l * 64, h, N, (l != 3) ? 1 : 0);
    }
    k_readout<<<gb, 256, 0, stream>>>(h, W0, b0, W1, b1, W2, b2, (float*)d_out, N);
}

// Round 11
// 314.929 us; speedup vs baseline: 1.6442x; 1.0774x over previous
//
#include <hip/hip_runtime.h>

typedef __attribute__((ext_vector_type(8))) short bf16x8_t;
typedef __attribute__((ext_vector_type(4))) float f32x4_t;

// ---------------- tiny zero ----------------

__global__ void k_zero(int* __restrict__ p, int n) {
    int i = threadIdx.x;
    if (i < n) p[i] = 0;
}

// ---------------- partition: edges -> coarse buckets (256 nodes each) ----------------

#define PCHUNK 8192
#define PTHREADS 512
#define NBUCK_MAX 400
#define BCAP 6144

__global__ __launch_bounds__(PTHREADS)
void k_partition2(const int* __restrict__ src, const int* __restrict__ dst,
                  int* __restrict__ bcnt, unsigned int* __restrict__ stageg,
                  int E, int nbuck) {
    __shared__ int hist[NBUCK_MAX];
    __shared__ int boffs[NBUCK_MAX];
    __shared__ int cur[NBUCK_MAX];
    __shared__ int gbase[NBUCK_MAX];
    __shared__ int tmp[PTHREADS];
    __shared__ unsigned int stage[PCHUNK];
    __shared__ unsigned short sbid[PCHUNK];

    int tid = threadIdx.x;
    int ebase = blockIdx.x * PCHUNK;
    int ecount = min(PCHUNK, E - ebase);

    if (tid < NBUCK_MAX) hist[tid] = 0;
    __syncthreads();

    int dreg[16], sreg[16];
#pragma unroll
    for (int k = 0; k < 16; k++) {
        int e = ebase + tid + k * PTHREADS;
        if (tid + k * PTHREADS < ecount) {
            dreg[k] = dst[e];
            sreg[k] = src[e];
            atomicAdd(&hist[dreg[k] >> 8], 1);
        } else dreg[k] = -1;
    }
    __syncthreads();

    int v = (tid < nbuck) ? hist[tid] : 0;
    tmp[tid] = v;
    __syncthreads();
    for (int d = 1; d < PTHREADS; d <<= 1) {
        int t = (tid >= d) ? tmp[tid - d] : 0;
        __syncthreads();
        tmp[tid] += t;
        __syncthreads();
    }
    if (tid < nbuck) { boffs[tid] = tmp[tid] - v; cur[tid] = tmp[tid] - v; }
    __syncthreads();

#pragma unroll
    for (int k = 0; k < 16; k++) {
        if (dreg[k] >= 0) {
            int b = dreg[k] >> 8;
            int p = atomicAdd(&cur[b], 1);
            stage[p] = ((unsigned int)(dreg[k] & 255) << 17) | (unsigned int)sreg[k];
            sbid[p] = (unsigned short)b;
        }
    }
    __syncthreads();

    if (tid < nbuck) {
        int c = cur[tid] - boffs[tid];
        if (c > 0) gbase[tid] = atomicAdd(&bcnt[tid], c);
    }
    __syncthreads();

    for (int i = tid; i < ecount; i += PTHREADS) {
        int b = sbid[i];
        stageg[(size_t)b * BCAP + gbase[b] + (i - boffs[b])] = stage[i];
    }
}

// ---------------- bucket scan ----------------

__global__ __launch_bounds__(512)
void k_bucket_scan(const int* __restrict__ bcnt, int* __restrict__ bbase, int nbuck) {
    __shared__ int tmp[512];
    int tid = threadIdx.x;
    int v = (tid < nbuck) ? bcnt[tid] : 0;
    tmp[tid] = v;
    __syncthreads();
    for (int d = 1; d < 512; d <<= 1) {
        int t = (tid >= d) ? tmp[tid - d] : 0;
        __syncthreads();
        tmp[tid] += t;
        __syncthreads();
    }
    if (tid < nbuck) bbase[tid] = tmp[tid] - v;
    if (tid == nbuck - 1) bbase[nbuck] = tmp[tid];
}

// ---------------- fine fill: bucket-staged -> dense CSR (offs, dinv, col) ----------------

__global__ __launch_bounds__(1024)
void k_finefill2(const unsigned int* __restrict__ stageg, const int* __restrict__ bcnt,
                 const int* __restrict__ bbase, int* __restrict__ offs,
                 float* __restrict__ dinv, int* __restrict__ col, int N, int nbuck) {
    __shared__ int cnt0[256];
    __shared__ int excl[256];
    __shared__ int cur[256];
    __shared__ unsigned int stage[BCAP];
    int b = blockIdx.x;
    int tid = threadIdx.x;
    int nbase = b << 8;
    int nn = min(256, N - nbase);
    int n = bcnt[b];
    int base = bbase[b];
    const unsigned int* sg = stageg + (size_t)b * BCAP;

    if (tid < 256) cnt0[tid] = 0;
    __syncthreads();

    for (int i = tid; i < n; i += 1024)
        atomicAdd(&cnt0[sg[i] >> 17], 1);
    __syncthreads();

    if (tid < 256) excl[tid] = cnt0[tid];
    __syncthreads();
    for (int d = 1; d < 256; d <<= 1) {
        int t = 0;
        if (tid < 256 && tid >= d) t = excl[tid - d];
        __syncthreads();
        if (tid < 256) excl[tid] += t;
        __syncthreads();
    }
    if (tid < 256) {
        int e = excl[tid] - cnt0[tid];
        cur[tid] = e;
        if (tid < nn) {
            offs[nbase + tid] = base + e;
            dinv[nbase + tid] = rsqrtf((float)(cnt0[tid] + 1));  // +1 self-loop
        }
    }
    if (b == nbuck - 1 && tid == 0) offs[N] = bbase[nbuck];
    __syncthreads();

    for (int i = tid; i < n; i += 1024) {
        unsigned int v = sg[i];
        int p = atomicAdd(&cur[v >> 17], 1);
        stage[p] = v & 0x1FFFFu;
    }
    __syncthreads();
    for (int i = tid; i < n; i += 1024)
        col[base + i] = (int)stage[i];
}

// ---------------- bf16 helpers ----------------

__device__ __forceinline__ unsigned int bf16rne(float x) {
    unsigned int u = __float_as_uint(x);
    return (u + 0x7FFFu + ((u >> 16) & 1u)) >> 16;
}
__device__ __forceinline__ float u2flo(unsigned int u) { return __uint_as_float(u << 16); }
__device__ __forceinline__ float u2fhi(unsigned int u) { return __uint_as_float(u & 0xFFFF0000u); }

// split a,b into packed bf16 hi and lo (residual) words
__device__ __forceinline__ void split2(float a, float b, unsigned int& hi, unsigned int& lo) {
    unsigned int ha = bf16rne(a), hb = bf16rne(b);
    float ra = a - u2flo(ha), rb = b - u2flo(hb);
    hi = ha | (hb << 16);
    lo = bf16rne(ra) | (bf16rne(rb) << 16);
}

union FragU { uint4 u4; bf16x8_t bf; };

// ---------------- MFMA GEMM: out[r][:] = (dinv[r]? * A[r][:]) @ W (+bias) ----------------
// Split-bf16 (hi+lo) on both operands -> fp32-equivalent accuracy, 3 MFMAs per tile-K.
// Block = 256 thr = 4 waves; wave = 32 rows x 64 cols (2 row-tiles x 4 col-tiles,
// K=64 as 2 chunks of 32). W staged per-block into LDS FRAGMENT-ORDERED (lane-indexed
// 16B slots -> aligned conflict-free ds_read_b128). dinv folded into A rows.
// Layouts: A lane l holds A[row=l&15][k=(l>>4)*8+j]; B lane l holds B[k][col=l&15];
// D lane l reg r = D[row=(l>>4)*4+r][col=l&15] (m89-verified). Within-frag k order
// cancels between A and B staging (same convention both sides).

template <bool HAS_BIAS, bool SCALE, bool OUTBF16>
__global__ __launch_bounds__(256, 4)
void k_gemm_mfma(const float* __restrict__ A, const float* __restrict__ W,
                 const float* __restrict__ bias, const float* __restrict__ scale,
                 void* __restrict__ out, int N) {
    __shared__ uint4 wfrag[16 * 64];  // (ct*2+kh)*2+p slots x 64 lanes, 16KB

    int tid = threadIdx.x;
    // ---- stage W (hi+lo) fragment-ordered ----
    {
        unsigned int* wb = (unsigned int*)wfrag;
#pragma unroll
        for (int i = 0; i < 16; i++) {
            int flat = tid * 16 + i;
            int m = flat & 3;
            int l = (flat >> 2) & 63;
            int fp = flat >> 8;        // 0..15
            int p = fp & 1;
            int f = fp >> 1;           // ct*2+kh
            int ct = f >> 1, kh = f & 1;
            int k = kh * 32 + ((l >> 4) << 3) + 2 * m;
            int c = ct * 16 + (l & 15);
            float w0 = W[k * 64 + c];
            float w1 = W[(k + 1) * 64 + c];
            unsigned int hi, lo;
            split2(w0, w1, hi, lo);
            wb[flat] = p ? lo : hi;
        }
    }
    __syncthreads();

    int lane = tid & 63;
    int wv = tid >> 6;
    int rowbase = blockIdx.x * 128 + wv * 32;

    // ---- build A fragments (hi+lo), dinv folded ----
    FragU ahi[2][2], alo[2][2];
#pragma unroll
    for (int rt = 0; rt < 2; rt++) {
        int row = rowbase + rt * 16 + (lane & 15);
        int rc = min(row, N - 1);
        float dv = SCALE ? scale[rc] : 1.0f;
#pragma unroll
        for (int kh = 0; kh < 2; kh++) {
            const float4* hp = (const float4*)(A + (size_t)rc * 64 + kh * 32 + ((lane >> 4) << 3));
            float4 p0 = hp[0], p1 = hp[1];
            p0.x *= dv; p0.y *= dv; p0.z *= dv; p0.w *= dv;
            p1.x *= dv; p1.y *= dv; p1.z *= dv; p1.w *= dv;
            split2(p0.x, p0.y, ahi[rt][kh].u4.x, alo[rt][kh].u4.x);
            split2(p0.z, p0.w, ahi[rt][kh].u4.y, alo[rt][kh].u4.y);
            split2(p1.x, p1.y, ahi[rt][kh].u4.z, alo[rt][kh].u4.z);
            split2(p1.z, p1.w, ahi[rt][kh].u4.w, alo[rt][kh].u4.w);
        }
    }

    // ---- accumulators ----
    f32x4_t acc[2][4];
#pragma unroll
    for (int ct = 0; ct < 4; ct++) {
        float b = HAS_BIAS ? bias[ct * 16 + (lane & 15)] : 0.0f;
#pragma unroll
        for (int rt = 0; rt < 2; rt++)
            acc[rt][ct] = (f32x4_t){b, b, b, b};
    }

    // ---- main MFMA loop ----
#pragma unroll
    for (int ct = 0; ct < 4; ct++) {
#pragma unroll
        for (int kh = 0; kh < 2; kh++) {
            FragU bhi, blo;
            bhi.u4 = wfrag[((ct * 2 + kh) * 2 + 0) * 64 + lane];
            blo.u4 = wfrag[((ct * 2 + kh) * 2 + 1) * 64 + lane];
#pragma unroll
            for (int rt = 0; rt < 2; rt++) {
                acc[rt][ct] = __builtin_amdgcn_mfma_f32_16x16x32_bf16(ahi[rt][kh].bf, bhi.bf, acc[rt][ct], 0, 0, 0);
                acc[rt][ct] = __builtin_amdgcn_mfma_f32_16x16x32_bf16(alo[rt][kh].bf, bhi.bf, acc[rt][ct], 0, 0, 0);
                acc[rt][ct] = __builtin_amdgcn_mfma_f32_16x16x32_bf16(ahi[rt][kh].bf, blo.bf, acc[rt][ct], 0, 0, 0);
            }
        }
    }

    // ---- epilogue ----
    if (OUTBF16) {
        unsigned short* ob = (unsigned short*)out;
#pragma unroll
        for (int rt = 0; rt < 2; rt++) {
#pragma unroll
            for (int ct = 0; ct < 4; ct++) {
#pragma unroll
                for (int r = 0; r < 4; r++) {
                    float v = acc[rt][ct][r];
                    float vo = __shfl_xor(v, 1);
                    int row = rowbase + rt * 16 + ((lane >> 4) << 2) + r;
                    if (!(lane & 1) && row < N) {
                        unsigned int pk = bf16rne(v) | (bf16rne(vo) << 16);
                        *(unsigned int*)(ob + (size_t)row * 64 + ct * 16 + (lane & 15)) = pk;
                    }
                }
            }
        }
    } else {
        float* of = (float*)out;
#pragma unroll
        for (int rt = 0; rt < 2; rt++) {
#pragma unroll
            for (int ct = 0; ct < 4; ct++) {
#pragma unroll
                for (int r = 0; r < 4; r++) {
                    int row = rowbase + rt * 16 + ((lane >> 4) << 2) + r;
                    if (row < N)
                        of[(size_t)row * 64 + ct * 16 + (lane & 15)] = acc[rt][ct][r];
                }
            }
        }
    }
}

// ---------------- Aggregation: one wave per 8 NODES (group=node, lane=8 channels) ----------------

__global__ __launch_bounds__(256)
void k_agg(const unsigned short* __restrict__ hwb, const int* __restrict__ offs,
           const int* __restrict__ col, const float* __restrict__ dinv,
           const float* __restrict__ bg, float* __restrict__ h, int N, int relu) {
    int t = blockIdx.x * blockDim.x + threadIdx.x;
    int wid = t >> 6;
    int lane = threadIdx.x & 63;
    int G = lane >> 3;
    int L = lane & 7;
    int node = wid * 8 + G;
    bool valid = node < N;
    int nc = valid ? node : N - 1;

    int start = offs[nc];
    int end = valid ? offs[nc + 1] : start;

    uint4 v = ((const uint4*)(hwb + (size_t)nc * 64))[L];
    float a0 = u2flo(v.x), a1 = u2fhi(v.x);
    float a2 = u2flo(v.y), a3 = u2fhi(v.y);
    float a4 = u2flo(v.z), a5 = u2fhi(v.z);
    float a6 = u2flo(v.w), a7 = u2fhi(v.w);

    for (int e = start;; e += 2) {
        bool act0 = e < end;
        if (__ballot(act0) == 0ULL) break;
        bool act1 = e + 1 < end;
        int e0 = act0 ? e : 0;
        int e1 = act1 ? e + 1 : 0;
        int s0 = col[e0];
        int s1 = col[e1];
        uint4 v0 = ((const uint4*)(hwb + (size_t)s0 * 64))[L];
        uint4 v1 = ((const uint4*)(hwb + (size_t)s1 * 64))[L];
        if (!act0) { v0.x = 0u; v0.y = 0u; v0.z = 0u; v0.w = 0u; }
        if (!act1) { v1.x = 0u; v1.y = 0u; v1.z = 0u; v1.w = 0u; }
        a0 += u2flo(v0.x) + u2flo(v1.x);
        a1 += u2fhi(v0.x) + u2fhi(v1.x);
        a2 += u2flo(v0.y) + u2flo(v1.y);
        a3 += u2fhi(v0.y) + u2fhi(v1.y);
        a4 += u2flo(v0.z) + u2flo(v1.z);
        a5 += u2fhi(v0.z) + u2fhi(v1.z);
        a6 += u2flo(v0.w) + u2flo(v1.w);
        a7 += u2fhi(v0.w) + u2fhi(v1.w);
    }

    if (valid) {
        float dn = dinv[node];
        float* hrow = h + (size_t)node * 64 + L * 8;
        float4 r0 = ((const float4*)hrow)[0];
        float4 r1 = ((const float4*)hrow)[1];
        const float* bgp = bg + L * 8;
        float4 b0 = ((const float4*)bgp)[0];
        float4 b1 = ((const float4*)bgp)[1];
        float4 o0, o1;
        o0.x = fmaf(dn, a0, b0.x + r0.x);
        o0.y = fmaf(dn, a1, b0.y + r0.y);
        o0.z = fmaf(dn, a2, b0.z + r0.z);
        o0.w = fmaf(dn, a3, b0.w + r0.w);
        o1.x = fmaf(dn, a4, b1.x + r1.x);
        o1.y = fmaf(dn, a5, b1.y + r1.y);
        o1.z = fmaf(dn, a6, b1.z + r1.z);
        o1.w = fmaf(dn, a7, b1.w + r1.w);
        if (relu) {
            o0.x = fmaxf(o0.x, 0.f); o0.y = fmaxf(o0.y, 0.f);
            o0.z = fmaxf(o0.z, 0.f); o0.w = fmaxf(o0.w, 0.f);
            o1.x = fmaxf(o1.x, 0.f); o1.y = fmaxf(o1.y, 0.f);
            o1.z = fmaxf(o1.z, 0.f); o1.w = fmaxf(o1.w, 0.f);
        }
        ((float4*)hrow)[0] = o0;
        ((float4*)hrow)[1] = o1;
    }
}

// ---------------- Fused MLP readout: 64 -> 32 -> 16 -> 1 (fully unrolled) ----------------

__global__ __launch_bounds__(256)
void k_readout(const float* __restrict__ h,
               const float* __restrict__ W0, const float* __restrict__ b0,
               const float* __restrict__ W1, const float* __restrict__ b1,
               const float* __restrict__ W2, const float* __restrict__ b2,
               float* __restrict__ out, int N) {
    int r = blockIdx.x * 256 + threadIdx.x;
    if (r >= N) return;

    float t0[32];
#pragma unroll
    for (int c = 0; c < 32; c++) t0[c] = b0[c];

    const float4* h4 = (const float4*)(h + (size_t)r * 64);
#pragma unroll
    for (int k4 = 0; k4 < 16; k4++) {
        float4 v = h4[k4];
#pragma unroll
        for (int kk = 0; kk < 4; kk++) {
            float xk = (kk == 0) ? v.x : (kk == 1) ? v.y : (kk == 2) ? v.z : v.w;
            const float* wr = W0 + (k4 * 4 + kk) * 32;
#pragma unroll
            for (int c = 0; c < 32; c++) t0[c] = fmaf(xk, wr[c], t0[c]);
        }
    }
#pragma unroll
    for (int c = 0; c < 32; c++) t0[c] = fmaxf(t0[c], 0.f);

    float t1[16];
#pragma unroll
    for (int c = 0; c < 16; c++) t1[c] = b1[c];
#pragma unroll
    for (int k = 0; k < 32; k++) {
        const float* wr = W1 + k * 16;
#pragma unroll
        for (int c = 0; c < 16; c++) t1[c] = fmaf(t0[k], wr[c], t1[c]);
    }
#pragma unroll
    for (int c = 0; c < 16; c++) t1[c] = fmaxf(t1[c], 0.f);

    float y = b2[0];
#pragma unroll
    for (int k = 0; k < 16; k++) y = fmaf(t1[k], W2[k], y);
    out[r] = y;
}

// ---------------- launch ----------------

extern "C" void kernel_launch(void* const* d_in, const int* in_sizes, int n_in,
                              void* d_out, int out_size, void* d_ws, size_t ws_size,
                              hipStream_t stream) {
    const float* x     = (const float*)d_in[0];
    const int*   eidx  = (const int*)d_in[1];
    const float* W_enc = (const float*)d_in[2];
    const float* b_enc = (const float*)d_in[3];
    const float* Wg    = (const float*)d_in[4];
    const float* bg    = (const float*)d_in[5];
    const float* W0    = (const float*)d_in[6];
    const float* b0    = (const float*)d_in[7];
    const float* W1    = (const float*)d_in[8];
    const float* b1    = (const float*)d_in[9];
    const float* W2    = (const float*)d_in[10];
    const float* b2    = (const float*)d_in[11];

    int N = in_sizes[0] / 64;
    int E = in_sizes[1] / 2;
    const int* esrc = eidx;
    const int* edst = eidx + E;
    int nbuck = (N + 255) >> 8;

    char* w = (char*)d_ws;
    auto alloc = [&](size_t bytes) -> char* {
        char* p = w;
        w += (bytes + 255) & ~(size_t)255;
        return p;
    };
    int*   bcnt  = (int*)alloc(512 * 4);
    int*   bbase = (int*)alloc(512 * 4);
    int*   offs  = (int*)alloc((size_t)(N + 1) * 4);
    int*   col   = (int*)alloc((size_t)E * 4);
    unsigned int* stageg = (unsigned int*)alloc((size_t)nbuck * BCAP * 4);
    float* dinv  = (float*)alloc((size_t)N * 4);
    float* h     = (float*)alloc((size_t)N * 64 * 4);
    unsigned short* hwb = (unsigned short*)alloc((size_t)N * 64 * 2);

    k_zero<<<1, 512, 0, stream>>>(bcnt, 512);
    k_partition2<<<(E + PCHUNK - 1) / PCHUNK, PTHREADS, 0, stream>>>(esrc, edst, bcnt, stageg, E, nbuck);
    k_bucket_scan<<<1, 512, 0, stream>>>(bcnt, bbase, nbuck);
    k_finefill2<<<nbuck, 1024, 0, stream>>>(stageg, bcnt, bbase, offs, dinv, col, N, nbuck);

    int gbM = (N + 127) / 128;      // MFMA GEMM: 128 rows per block
    int gb = (N + 255) / 256;
    int aggthreads = ((N + 7) / 8) * 64;
    int aggblocks = (aggthreads + 255) / 256;
    k_gemm_mfma<true, false, false><<<gbM, 256, 0, stream>>>(x, W_enc, b_enc, nullptr, h, N);
    for (int l = 0; l < 4; l++) {
        k_gemm_mfma<false, true, true><<<gbM, 256, 0, stream>>>(h, Wg + (size_t)l * 4096, nullptr, dinv, hwb, N);
        k_agg<<<aggblocks, 256, 0, stream>>>(
            hwb, offs, col, dinv, bg + (size_t)l * 64, h, N, (l != 3) ? 1 : 0);
    }
    k_readout<<<gb, 256, 0, stream>>>(h, W0, b0, W1, b1, W2, b2, (float*)d_out, N);
}